// Round 2
// baseline (2470.469 us; speedup 1.0000x reference)
//
#include <hip/hip_runtime.h>

#define D_    256
#define V_    32
#define HW_   (512*512)
#define OUTF_ 256

// ---------------------------------------------------------------------------
// K1: per-pixel Q logits + softmax. Q[p,i] = sum_d ((x_pd - W_di)*iv_di)^2
// via e = fmaf(x, iv, -(W*iv)); acc += e*e.
// A=W*iv, B=iv in LDS as float4 (broadcast ds_read_b128).
// 4 pixels/thread: per d, 16 b128 serve 256 FMA insts (16:1).
// block=128, grid=512 -> 2 blocks/CU (64KB LDS each).
// ---------------------------------------------------------------------------
__global__ __launch_bounds__(128, 1) void k1_q(const float* __restrict__ X,
                                               const float* __restrict__ W,
                                               const float* __restrict__ var,
                                               float* __restrict__ Q)
{
    __shared__ float4 As4[D_][8];   // W * iv
    __shared__ float4 Bs4[D_][8];   // iv
    const int t = threadIdx.x;

    for (int r = t; r < D_; r += 128) {
        const float4* wr = (const float4*)(W   + r * V_);
        const float4* vr = (const float4*)(var + r * V_);
        #pragma unroll
        for (int i4 = 0; i4 < 8; ++i4) {
            float4 wv = wr[i4], vv = vr[i4];
            float4 iv;
            iv.x = 1.0f / vv.x; iv.y = 1.0f / vv.y;
            iv.z = 1.0f / vv.z; iv.w = 1.0f / vv.w;
            float4 a;
            a.x = wv.x * iv.x; a.y = wv.y * iv.y;
            a.z = wv.z * iv.z; a.w = wv.w * iv.w;
            As4[r][i4] = a;
            Bs4[r][i4] = iv;
        }
    }
    __syncthreads();

    const size_t pbase = (size_t)blockIdx.x * 512 + t;   // pixels: pbase + 128*j
    const float* xp = X + pbase * D_;

    float acc[4][V_];
    #pragma unroll
    for (int j = 0; j < 4; ++j)
        #pragma unroll
        for (int i = 0; i < V_; ++i) acc[j][i] = 0.f;

    #pragma unroll 2
    for (int d4 = 0; d4 < D_/4; ++d4) {
        float4 xv[4];
        #pragma unroll
        for (int j = 0; j < 4; ++j)
            xv[j] = *(const float4*)(xp + (size_t)j * 128 * D_ + d4 * 4);
        #pragma unroll
        for (int k = 0; k < 4; ++k) {
            const int d = d4 * 4 + k;
            #pragma unroll
            for (int i4 = 0; i4 < 8; ++i4) {
                const float4 a4 = As4[d][i4];
                const float4 b4 = Bs4[d][i4];
                #pragma unroll
                for (int j = 0; j < 4; ++j) {
                    const float xk = (k == 0) ? xv[j].x : (k == 1) ? xv[j].y
                                   : (k == 2) ? xv[j].z : xv[j].w;
                    float e0 = fmaf(xk, b4.x, -a4.x);
                    float e1 = fmaf(xk, b4.y, -a4.y);
                    float e2 = fmaf(xk, b4.z, -a4.z);
                    float e3 = fmaf(xk, b4.w, -a4.w);
                    acc[j][i4*4+0] = fmaf(e0, e0, acc[j][i4*4+0]);
                    acc[j][i4*4+1] = fmaf(e1, e1, acc[j][i4*4+1]);
                    acc[j][i4*4+2] = fmaf(e2, e2, acc[j][i4*4+2]);
                    acc[j][i4*4+3] = fmaf(e3, e3, acc[j][i4*4+3]);
                }
            }
        }
    }

    // softmax per pixel, in place; then store
    #pragma unroll
    for (int j = 0; j < 4; ++j) {
        float mn = 3.4e38f;
        #pragma unroll
        for (int i = 0; i < V_; ++i) mn = fminf(mn, acc[j][i]);
        float sum = 0.f;
        #pragma unroll
        for (int i = 0; i < V_; ++i) {
            float q = __expf(-0.5f * (acc[j][i] - mn));
            acc[j][i] = q;
            sum += q;
        }
        const float inv = 1.0f / sum;
        float* qout = Q + (pbase + (size_t)j * 128) * V_;
        #pragma unroll
        for (int i4 = 0; i4 < 8; ++i4) {
            float4 o;
            o.x = acc[j][i4*4+0] * inv; o.y = acc[j][i4*4+1] * inv;
            o.z = acc[j][i4*4+2] * inv; o.w = acc[j][i4*4+3] * inv;
            *(float4*)(qout + i4 * 4) = o;
        }
    }
}

// ---------------------------------------------------------------------------
// K2: M[d,i] = sum_p X[p,d]*Q[p,i]  and  s[i] = sum_p Q[p,i].
// Single-wave blocks (64 threads); thread t owns d = 4t..4t+3.
// 128 pixels/block, Q staged in LDS 64 px at a time (coalesced), X loads
// float4 fully coalesced. Per pixel: 8 b128 broadcast + 128 FMA (16:1).
// ---------------------------------------------------------------------------
__global__ __launch_bounds__(64, 2) void k2_m(const float* __restrict__ X,
                                              const float* __restrict__ Q,
                                              float* __restrict__ M,
                                              float* __restrict__ s_out)
{
    __shared__ float4 Qs[64][8];
    const int t = threadIdx.x;
    const size_t p0 = (size_t)blockIdx.x * 128;

    float acc[4][V_];
    #pragma unroll
    for (int k = 0; k < 4; ++k)
        #pragma unroll
        for (int i = 0; i < V_; ++i) acc[k][i] = 0.f;

    float sacc = 0.f;
    const int si = t & 31, sh = t >> 5;

    for (int ch = 0; ch < 2; ++ch) {
        const size_t pc = p0 + ch * 64;
        const float4* qsrc = (const float4*)(Q + pc * V_);
        #pragma unroll
        for (int j = 0; j < 8; ++j) {
            int L = j * 64 + t;
            Qs[L >> 3][L & 7] = qsrc[L];
        }
        __syncthreads();

        // s partial: half-wave sh sums 32 pixels, column si
        #pragma unroll 4
        for (int pp = 0; pp < 32; ++pp)
            sacc += ((const float*)&Qs[sh * 32 + pp][0])[si];

        #pragma unroll 2
        for (int pp = 0; pp < 64; ++pp) {
            const float4 x4 = *(const float4*)(X + (pc + pp) * D_ + 4 * t);
            #pragma unroll
            for (int i4 = 0; i4 < 8; ++i4) {
                const float4 q4 = Qs[pp][i4];
                #pragma unroll
                for (int c = 0; c < 4; ++c) {
                    const float qv = (c == 0) ? q4.x : (c == 1) ? q4.y
                                   : (c == 2) ? q4.z : q4.w;
                    acc[0][i4*4+c] = fmaf(x4.x, qv, acc[0][i4*4+c]);
                    acc[1][i4*4+c] = fmaf(x4.y, qv, acc[1][i4*4+c]);
                    acc[2][i4*4+c] = fmaf(x4.z, qv, acc[2][i4*4+c]);
                    acc[3][i4*4+c] = fmaf(x4.w, qv, acc[3][i4*4+c]);
                }
            }
        }
        __syncthreads();
    }

    #pragma unroll
    for (int k = 0; k < 4; ++k)
        #pragma unroll
        for (int i = 0; i < V_; ++i)
            atomicAdd(&M[(4 * t + k) * V_ + i], acc[k][i]);

    sacc += __shfl_down(sacc, 32);
    if (t < V_) atomicAdd(&s_out[t], sacc);
}

// ---------------------------------------------------------------------------
// K3a: Z = (M - W*s)*iv/s ; Z /= sum_d Z^2 (per column) ; Adj = Z^T Z
// ---------------------------------------------------------------------------
__global__ __launch_bounds__(256) void k3a(const float* __restrict__ M,
                                           const float* __restrict__ s_in,
                                           const float* __restrict__ W,
                                           const float* __restrict__ var,
                                           float* __restrict__ Z,
                                           float* __restrict__ Adj)
{
    __shared__ float Zl[D_][V_];
    __shared__ float ss[V_];
    __shared__ float nrm[V_];
    const int t = threadIdx.x;
    if (t < V_) ss[t] = s_in[t];
    __syncthreads();

    #pragma unroll
    for (int i = 0; i < V_; ++i) {
        float iv = 1.0f / var[t*V_ + i];
        Zl[t][i] = (M[t*V_ + i] - W[t*V_ + i] * ss[i]) * iv / ss[i];
    }
    __syncthreads();
    if (t < V_) {
        float n = 0.f;
        for (int d = 0; d < D_; ++d) { float z = Zl[d][t]; n = fmaf(z, z, n); }
        nrm[t] = n;
    }
    __syncthreads();
    #pragma unroll
    for (int i = 0; i < V_; ++i) {
        float z = Zl[t][i] / nrm[i];
        Zl[t][i] = z;
        Z[t*V_ + i] = z;
    }
    __syncthreads();
    #pragma unroll
    for (int e = 0; e < 4; ++e) {
        int idx = t*4 + e;
        int i = idx >> 5, j = idx & 31;
        float a = 0.f;
        for (int d = 0; d < D_; ++d) a = fmaf(Zl[d][i], Zl[d][j], a);
        Adj[idx] = a;
    }
}

// ---------------------------------------------------------------------------
// K3b: T[j] = sum_d Z[d,j]*weight[d,f] ; Zo[i,f] = relu(sum_j Adj[i,j]*T[j])
// ---------------------------------------------------------------------------
__global__ __launch_bounds__(256) void k3b(const float* __restrict__ Z,
                                           const float* __restrict__ weight,
                                           const float* __restrict__ Adj,
                                           float* __restrict__ Zo)
{
    __shared__ float T[V_];
    const int t = threadIdx.x;
    const int f = blockIdx.x;
    if (t < V_) T[t] = 0.f;
    __syncthreads();
    const float wt = weight[t*OUTF_ + f];
    const float* zr = Z + t*V_;
    #pragma unroll
    for (int j = 0; j < V_; ++j) atomicAdd(&T[j], zr[j] * wt);
    __syncthreads();
    if (t < V_) {
        float o = 0.f;
        #pragma unroll
        for (int j = 0; j < V_; ++j) o = fmaf(Adj[t*V_ + j], T[j], o);
        Zo[t*OUTF_ + f] = fmaxf(o, 0.f);
    }
}

// ---------------------------------------------------------------------------
// K4: out[p,f] = sum_i Q[p,i]*Zo[i,f]. Thread owns f-quad (Zo column slice in
// 128 VGPRs, float4 stores). Wave w handles pixel subset [w*64, w*64+64) so
// each Q row is broadcast-read by exactly one wave. Q tile (256px) in LDS.
// ---------------------------------------------------------------------------
__global__ __launch_bounds__(256, 2) void k4_out(const float* __restrict__ Q,
                                                 const float* __restrict__ Zo,
                                                 float* __restrict__ out)
{
    __shared__ float4 Qt[256][8];
    const int t  = threadIdx.x;
    const int fq = t & 63;          // f = 4*fq .. 4*fq+3
    const int w  = t >> 6;
    const size_t p0 = (size_t)blockIdx.x * 256;

    float4 zc[V_];
    #pragma unroll
    for (int i = 0; i < V_; ++i)
        zc[i] = *(const float4*)(Zo + i * OUTF_ + 4 * fq);

    const float4* qsrc = (const float4*)(Q + p0 * V_);
    #pragma unroll
    for (int j = 0; j < 8; ++j) {
        int L = j * 256 + t;
        Qt[L >> 3][L & 7] = qsrc[L];
    }
    __syncthreads();

    #pragma unroll 2
    for (int pp = w * 64; pp < w * 64 + 64; ++pp) {
        float4 a; a.x = 0.f; a.y = 0.f; a.z = 0.f; a.w = 0.f;
        #pragma unroll
        for (int i4 = 0; i4 < 8; ++i4) {
            const float4 q4 = Qt[pp][i4];
            #pragma unroll
            for (int c = 0; c < 4; ++c) {
                const float qv = (c == 0) ? q4.x : (c == 1) ? q4.y
                               : (c == 2) ? q4.z : q4.w;
                const float4 z4 = zc[i4*4+c];
                a.x = fmaf(qv, z4.x, a.x);
                a.y = fmaf(qv, z4.y, a.y);
                a.z = fmaf(qv, z4.z, a.z);
                a.w = fmaf(qv, z4.w, a.w);
            }
        }
        *(float4*)(out + (p0 + pp) * OUTF_ + 4 * fq) = a;
    }
}

extern "C" void kernel_launch(void* const* d_in, const int* in_sizes, int n_in,
                              void* d_out, int out_size, void* d_ws, size_t ws_size,
                              hipStream_t stream)
{
    const float* X      = (const float*)d_in[0];
    const float* W      = (const float*)d_in[1];
    const float* var    = (const float*)d_in[2];
    const float* weight = (const float*)d_in[3];
    float* out = (float*)d_out;
    float* ws  = (float*)d_ws;

    float* Q   = ws;                         // HW_*V_ floats (32 MB)
    float* s   = Q   + (size_t)HW_ * V_;     // 32
    float* M   = s   + V_;                   // D_*V_
    float* Z   = M   + D_ * V_;              // D_*V_
    float* Adj = Z   + D_ * V_;              // V_*V_
    float* Zo  = Adj + V_ * V_;              // V_*OUTF_

    hipMemsetAsync(s, 0, (V_ + D_*V_) * sizeof(float), stream);

    k1_q  <<<512,      128, 0, stream>>>(X, W, var, Q);
    k2_m  <<<HW_/128,  64,  0, stream>>>(X, Q, M, s);
    k3a   <<<1,        256, 0, stream>>>(M, s, W, var, Z, Adj);
    k3b   <<<OUTF_,    256, 0, stream>>>(Z, weight, Adj, Zo);
    k4_out<<<HW_/256,  256, 0, stream>>>(Q, Zo, out);
}